// Round 6
// baseline (281.560 us; speedup 1.0000x reference)
//
#include <hip/hip_runtime.h>
#include <hip/hip_bf16.h>
#include <stdint.h>

#define B_ 4
#define S_ 2048
#define DM_ 768
#define H_ 12
#define HD_ 64
#define ROWS (B_*S_)      // 8192
#define QKVN (3*DM_)      // 2304

typedef __attribute__((ext_vector_type(8))) short short8;
typedef __attribute__((ext_vector_type(4))) float floatx4;
typedef __attribute__((ext_vector_type(8))) unsigned short ushort8;
typedef __attribute__((ext_vector_type(4))) unsigned short ushort4v;
typedef __attribute__((ext_vector_type(4))) float float4_t;

__device__ __forceinline__ unsigned short f2b(float f) {
  union { float f; uint32_t u; } x; x.f = f;
  uint32_t r = x.u + 0x7FFFu + ((x.u >> 16) & 1u);
  return (unsigned short)(r >> 16);
}
__device__ __forceinline__ uint32_t fbits(float f) {
  union { float f; uint32_t u; } x; x.f = f; return x.u;
}

// async global->LDS, 16B per lane. LDS dest is wave-uniform base + lane*16.
__device__ __forceinline__ void load_lds16(const void* g, void* l) {
  __builtin_amdgcn_global_load_lds(
      (const __attribute__((address_space(1))) uint32_t*)g,
      (__attribute__((address_space(3))) uint32_t*)l, 16, 0, 0);
}

// ---------------- fused prep: base cast + 3 weight transposes ----------------
// block ranges: [0,6144) cvt | [6144,7872) Wqkv | [7872,8448) W1 | [8448,9024) W2
#define CVT_B 6144
#define WQ_B 1728
#define W1_B 576
__global__ __launch_bounds__(256) void prep(
    const float* __restrict__ base, unsigned short* __restrict__ base_bf,
    const float* __restrict__ Wqkv, unsigned short* __restrict__ Wqkvt,
    const float* __restrict__ W1, unsigned short* __restrict__ W1t,
    const float* __restrict__ W2, unsigned short* __restrict__ W2t) {
  __shared__ float t[32][33];
  int bid = blockIdx.x;
  int tid = threadIdx.x;
  if (bid < CVT_B) {
    int i = bid * 256 + tid;
    float4_t v = ((const float4_t*)base)[i];
    ushort4v o;
    o[0] = f2b(v[0]); o[1] = f2b(v[1]); o[2] = f2b(v[2]); o[3] = f2b(v[3]);
    ((ushort4v*)base_bf)[i] = o;
    return;
  }
  const float* W; unsigned short* Wt; int N, rel;
  if (bid < CVT_B + WQ_B)      { W = Wqkv; Wt = Wqkvt; N = QKVN; rel = bid - CVT_B; }
  else if (bid < CVT_B + WQ_B + W1_B) { W = W1; Wt = W1t; N = DM_; rel = bid - CVT_B - WQ_B; }
  else                          { W = W2; Wt = W2t; N = DM_; rel = bid - CVT_B - WQ_B - W1_B; }
  int K = DM_;
  int n0 = (rel % (N / 32)) * 32, k0 = (rel / (N / 32)) * 32;
  int tx = tid & 31, ty = tid >> 5;  // ty 0..7
#pragma unroll
  for (int i = 0; i < 4; i++)
    t[ty + i * 8][tx] = W[(size_t)(k0 + ty + i * 8) * N + n0 + tx];
  __syncthreads();
#pragma unroll
  for (int i = 0; i < 4; i++)
    Wt[(size_t)(n0 + ty + i * 8) * K + k0 + tx] = f2b(t[tx][ty + i * 8]);
}

// ---------------- V slice of qkv -> Vt [b*H+h][d][s-tiles, permuted] bf16 ----------------
// within each 64-key tile, output position p holds key s = ((p&3)<<4)|(p>>2)
// (forward: key s lands at pos (s&15)*4 + (s>>4)) — matches attn's packed-P column order.
__global__ __launch_bounds__(256) void vtrans(const unsigned short* __restrict__ qkv,
                                              unsigned short* __restrict__ Vt) {
  int st = blockIdx.x;   // s-tile 0..31
  int bh = blockIdx.y;   // 0..47
  int b = bh / H_, h = bh % H_;
  __shared__ unsigned short t[64][65];
  int tid = threadIdx.x;
#pragma unroll
  for (int i = 0; i < 2; i++) {
    int c = i * 256 + tid;
    int r = c >> 3, o = (c & 7) * 8;
    ushort8 v = *(const ushort8*)(qkv + (size_t)(b * S_ + st * 64 + r) * QKVN + 2 * DM_ + h * HD_ + o);
#pragma unroll
    for (int j = 0; j < 8; j++) t[r][o + j] = v[j];
  }
  __syncthreads();
#pragma unroll
  for (int i = 0; i < 2; i++) {
    int c = i * 256 + tid;
    int d = c >> 3, o = (c & 7) * 8;
    ushort8 v;
#pragma unroll
    for (int j = 0; j < 8; j++) {
      int p = o + j;
      int s = ((p & 3) << 4) | (p >> 2);
      v[j] = t[s][d];
    }
    *(ushort8*)(Vt + (size_t)(bh * 64 + d) * S_ + st * 64 + o) = v;
  }
}

// ---------------- bf16 MFMA GEMM (64x128 tile, 4 blocks/CU) ----------------
// XOR-swizzled LDS: chunk c of row r stored at position c^(r&7); staging permutes the
// global source chunk within each 128B segment (still coalesced); frag reads conflict-free.
template <int EPI>
__global__ __launch_bounds__(256, 4) void gemm64(
    const unsigned short* __restrict__ A,
    const unsigned short* __restrict__ Bt,
    const float* __restrict__ bias,
    const float* __restrict__ res,
    void* __restrict__ Cout,
    int M, int N, int K) {
  __shared__ __align__(16) unsigned short As[64 * 64];
  __shared__ __align__(16) unsigned short Bs[128 * 64];
  int tid = threadIdx.x;
  int wave = tid >> 6, lane = tid & 63;
  int quad = lane >> 4, l16 = lane & 15;
  int e = l16 & 7;
  int sr = lane >> 3;
  int sc = (lane & 7) ^ (sr & 7);
  int m0 = blockIdx.y * 64, n0 = blockIdx.x * 128;
  int wm = (wave >> 1) * 32, wn = (wave & 1) * 64;
  floatx4 acc[2][4] = {};

  for (int kb = 0; kb < K; kb += 64) {
#pragma unroll
    for (int i = 0; i < 2; i++) {
      int op = wave * 2 + i;  // 8 A ops
      load_lds16(A + (size_t)(m0 + op * 8 + sr) * K + kb + sc * 8, (char*)As + op * 1024);
    }
#pragma unroll
    for (int i = 0; i < 4; i++) {
      int op = wave * 4 + i;  // 16 B ops
      load_lds16(Bt + (size_t)(n0 + op * 8 + sr) * K + kb + sc * 8, (char*)Bs + op * 1024);
    }
    __syncthreads();
#pragma unroll
    for (int ks = 0; ks < 2; ks++) {
      short8 af[2], bfr[4];
#pragma unroll
      for (int mt = 0; mt < 2; mt++)
        af[mt] = *(const short8*)(As + (wm + mt * 16 + l16) * 64 + ((ks * 4 + quad) ^ e) * 8);
#pragma unroll
      for (int nt = 0; nt < 4; nt++)
        bfr[nt] = *(const short8*)(Bs + (wn + nt * 16 + l16) * 64 + ((ks * 4 + quad) ^ e) * 8);
#pragma unroll
      for (int mt = 0; mt < 2; mt++)
#pragma unroll
        for (int nt = 0; nt < 4; nt++)
          acc[mt][nt] = __builtin_amdgcn_mfma_f32_16x16x32_bf16(af[mt], bfr[nt], acc[mt][nt], 0, 0, 0);
    }
    __syncthreads();
  }
#pragma unroll
  for (int mt = 0; mt < 2; mt++) {
#pragma unroll
    for (int nt = 0; nt < 4; nt++) {
#pragma unroll
      for (int r = 0; r < 4; r++) {
        int row = m0 + wm + mt * 16 + quad * 4 + r;
        int col = n0 + wn + nt * 16 + l16;
        size_t idx = (size_t)row * N + col;
        float v = acc[mt][nt][r] + bias[col];
        if (EPI == 0) {
          ((unsigned short*)Cout)[idx] = f2b(v);
        } else if (EPI == 1) {
          ((float*)Cout)[idx] = v + res[idx];
        } else {
          ((float*)Cout)[idx] = fmaxf(v, 0.0f) + res[idx];
        }
      }
    }
  }
}

// ---------------- flash attention: av = softmax(Q K^T / 8) V ----------------
// 2 waves/block, 64 q-rows/wave (mf=4): each K/V frag read feeds 4 MFMAs (was 2),
// cutting per-block LDS reads 2560->1536. LDS 50.4 KB -> 3 blocks/CU; grid 768 =
// exactly one balanced round. Q staged into each wave's private Ps slab (read once
// into regs, space reused for P). XOR-swizzled Ks/Vs; P packed 4-wide (permuted key
// order matching Vt) via v_perm, written as ds_write_b64; no running max (scores
// small, softmax shift-invariant); denominator via MFMA with ones.
__global__ __launch_bounds__(128, 2) void attn(
    const unsigned short* __restrict__ qkv,
    const unsigned short* __restrict__ Vt,
    unsigned short* __restrict__ av) {
  int qt = blockIdx.x;   // q-tile 0..15 (128 rows)
  int bh = blockIdx.y;   // 0..47
  int b = bh / H_, h = bh % H_;
  int row0 = b * S_ + qt * 128;
  __shared__ __align__(16) unsigned short Ks[2][64 * 64];
  __shared__ __align__(16) unsigned short Vs[2][64 * 64];
  __shared__ __align__(16) unsigned short Ps[2][64 * 72];  // row stride 144B; doubles as Q staging
  int tid = threadIdx.x;
  int wave = tid >> 6, lane = tid & 63;
  int quad = lane >> 4, l16 = lane & 15;
  int e = l16 & 7;
  int sr = lane >> 3;
  int sc = (lane & 7) ^ (sr & 7);

  // stage this wave's 64 Q rows into its own Ps slab (row stride 128B, swizzled chunks)
#pragma unroll
  for (int i = 0; i < 8; i++) {
    load_lds16(qkv + (size_t)(row0 + wave * 64 + i * 8 + sr) * QKVN + h * HD_ + sc * 8,
               (char*)Ps[wave] + i * 1024);
  }
  auto stageKV = [&](int kt, int buf) {
#pragma unroll
    for (int i = 0; i < 4; i++) {
      int op = wave * 4 + i;
      load_lds16(qkv + (size_t)(b * S_ + kt * 64 + op * 8 + sr) * QKVN + DM_ + h * HD_ + sc * 8,
                 (char*)Ks[buf] + op * 1024);
      load_lds16(Vt + (size_t)(bh * 64 + op * 8 + sr) * S_ + kt * 64 + sc * 8,
                 (char*)Vs[buf] + op * 1024);
    }
  };
  stageKV(0, 0);

  floatx4 accO[4][4] = {};
  floatx4 accL[4] = {};
  const float scl = 0.125f * 1.44269504088896340736f;  // 1/sqrt(64) * log2(e)
  short8 ones;
#pragma unroll
  for (int j = 0; j < 8; j++) ones[j] = (short)0x3F80;  // bf16 1.0
  __syncthreads();  // Q + KV(0) staged (drains vmcnt)

  // hoist Q fragments from this wave's Ps slab (before any P write; same-wave ordering)
  short8 qf[4][2];
#pragma unroll
  for (int mf = 0; mf < 4; mf++)
#pragma unroll
    for (int ks = 0; ks < 2; ks++)
      qf[mf][ks] = *(const short8*)(Ps[wave] + (mf * 16 + l16) * 64 + ((ks * 4 + quad) ^ e) * 8);

  int cur = 0;
  for (int kt = 0; kt < 32; kt++) {
    floatx4 sv[4][4] = {};
#pragma unroll
    for (int ks = 0; ks < 2; ks++)
#pragma unroll
      for (int nt = 0; nt < 4; nt++) {
        short8 kf = *(const short8*)(Ks[cur] + (nt * 16 + l16) * 64 + ((ks * 4 + quad) ^ e) * 8);
#pragma unroll
        for (int mf = 0; mf < 4; mf++)
          sv[mf][nt] = __builtin_amdgcn_mfma_f32_16x16x32_bf16(qf[mf][ks], kf, sv[mf][nt], 0, 0, 0);
      }
    // prefetch next K/V now: overlaps softmax + PV below
    if (kt + 1 < 32) stageKV(kt + 1, cur ^ 1);
    // p = exp2(s*scl); pack 4 bf16 (keys nt*16+l16 -> contiguous pos 4*l16+nt) -> b64 write
#pragma unroll
    for (int mf = 0; mf < 4; mf++)
#pragma unroll
      for (int r = 0; r < 4; r++) {
        uint32_t u0 = fbits(__builtin_amdgcn_exp2f(sv[mf][0][r] * scl));
        uint32_t u1 = fbits(__builtin_amdgcn_exp2f(sv[mf][1][r] * scl));
        uint32_t u2 = fbits(__builtin_amdgcn_exp2f(sv[mf][2][r] * scl));
        uint32_t u3 = fbits(__builtin_amdgcn_exp2f(sv[mf][3][r] * scl));
        uint2 val;
        val.x = __builtin_amdgcn_perm(u1, u0, 0x07060302u);  // [u0.hi16, u1.hi16]
        val.y = __builtin_amdgcn_perm(u3, u2, 0x07060302u);  // [u2.hi16, u3.hi16]
        *(uint2*)(&Ps[wave][(mf * 16 + quad * 4 + r) * 72 + l16 * 4]) = val;
      }
#pragma unroll
    for (int ks = 0; ks < 2; ks++) {
      short8 pf[4];
#pragma unroll
      for (int mf = 0; mf < 4; mf++) {
        pf[mf] = *(const short8*)(Ps[wave] + (mf * 16 + l16) * 72 + ks * 32 + quad * 8);
        accL[mf] = __builtin_amdgcn_mfma_f32_16x16x32_bf16(pf[mf], ones, accL[mf], 0, 0, 0);
      }
#pragma unroll
      for (int nt = 0; nt < 4; nt++) {
        short8 vf = *(const short8*)(Vs[cur] + (nt * 16 + l16) * 64 + ((ks * 4 + quad) ^ e) * 8);
#pragma unroll
        for (int mf = 0; mf < 4; mf++)
          accO[mf][nt] = __builtin_amdgcn_mfma_f32_16x16x32_bf16(pf[mf], vf, accO[mf][nt], 0, 0, 0);
      }
    }
    __syncthreads();  // drains prefetch vmcnt; all waves done with cur
    cur ^= 1;
  }
#pragma unroll
  for (int mf = 0; mf < 4; mf++)
#pragma unroll
    for (int r = 0; r < 4; r++) {
      float inv = 1.0f / accL[mf][r];
      int row = row0 + wave * 64 + mf * 16 + quad * 4 + r;
#pragma unroll
      for (int nt = 0; nt < 4; nt++)
        av[(size_t)row * DM_ + h * HD_ + nt * 16 + l16] = f2b(accO[mf][nt][r] * inv);
    }
}

// ---------------- row norm: (x-mean)/std * scale + bias ----------------
template <int WB>
__global__ __launch_bounds__(256) void normk(
    const float* __restrict__ X, const float* __restrict__ scale,
    const float* __restrict__ bias, float* __restrict__ Y,
    unsigned short* __restrict__ Ybf) {
  int row = blockIdx.x;
  const float* x = X + (size_t)row * DM_;
  int tid = threadIdx.x;
  int wave = tid >> 6, lane = tid & 63;
  float v[3];
#pragma unroll
  for (int i = 0; i < 3; i++) v[i] = x[tid + i * 256];
  float s = v[0] + v[1] + v[2];
#pragma unroll
  for (int o = 32; o > 0; o >>= 1) s += __shfl_xor(s, o);
  __shared__ float red[4];
  if (lane == 0) red[wave] = s;
  __syncthreads();
  float mean = (red[0] + red[1] + red[2] + red[3]) * (1.0f / DM_);
  float ss = 0.0f;
#pragma unroll
  for (int i = 0; i < 3; i++) { v[i] -= mean; ss += v[i] * v[i]; }
#pragma unroll
  for (int o = 32; o > 0; o >>= 1) ss += __shfl_xor(ss, o);
  __syncthreads();
  if (lane == 0) red[wave] = ss;
  __syncthreads();
  float var = (red[0] + red[1] + red[2] + red[3]) * (1.0f / DM_);
  float rstd = rsqrtf(var);
  float sg = scale[0], bg = bias[0];
#pragma unroll
  for (int i = 0; i < 3; i++) {
    float y = v[i] * rstd * sg + bg;
    Y[(size_t)row * DM_ + tid + i * 256] = y;
    if (WB) Ybf[(size_t)row * DM_ + tid + i * 256] = f2b(y);
  }
}

extern "C" void kernel_launch(void* const* d_in, const int* in_sizes, int n_in,
                              void* d_out, int out_size, void* d_ws, size_t ws_size,
                              hipStream_t stream) {
  const float* base = (const float*)d_in[0];
  const float* Wqkv = (const float*)d_in[1];
  const float* bqkv = (const float*)d_in[2];
  const float* W1 = (const float*)d_in[3];
  const float* b1 = (const float*)d_in[4];
  const float* W2 = (const float*)d_in[5];
  const float* b2 = (const float*)d_in[6];
  const float* n1s = (const float*)d_in[7];
  const float* n1b = (const float*)d_in[8];
  const float* n2s = (const float*)d_in[9];
  const float* n2b = (const float*)d_in[10];
  float* out = (float*)d_out;

  char* ws = (char*)d_ws;
  size_t off = 0;
  auto alloc = [&](size_t bytes) {
    char* p = ws + off;
    off = (off + bytes + 255) & ~(size_t)255;
    return p;
  };
  unsigned short* base_bf = (unsigned short*)alloc((size_t)ROWS * DM_ * 2);
  unsigned short* Wqkvt = (unsigned short*)alloc((size_t)QKVN * DM_ * 2);
  unsigned short* W1t = (unsigned short*)alloc((size_t)DM_ * DM_ * 2);
  unsigned short* W2t = (unsigned short*)alloc((size_t)DM_ * DM_ * 2);
  unsigned short* qkvb = (unsigned short*)alloc((size_t)ROWS * QKVN * 2);
  unsigned short* Vtb = (unsigned short*)alloc((size_t)B_ * H_ * HD_ * S_ * 2);
  unsigned short* avb = (unsigned short*)alloc((size_t)ROWS * DM_ * 2);
  float* t1 = (float*)alloc((size_t)ROWS * DM_ * 4);        // reused for t2
  float* hidden = (float*)alloc((size_t)ROWS * DM_ * 4);
  unsigned short* hbf = (unsigned short*)alloc((size_t)ROWS * DM_ * 2);

  prep<<<CVT_B + WQ_B + 2 * W1_B, 256, 0, stream>>>(
      base, base_bf, Wqkv, Wqkvt, W1, W1t, W2, W2t);
  gemm64<0><<<dim3(QKVN / 128, ROWS / 64), 256, 0, stream>>>(
      base_bf, Wqkvt, bqkv, nullptr, qkvb, ROWS, QKVN, DM_);
  vtrans<<<dim3(S_ / 64, B_ * H_), 256, 0, stream>>>(qkvb, Vtb);
  attn<<<dim3(S_ / 128, B_ * H_), 128, 0, stream>>>(qkvb, Vtb, avb);
  gemm64<1><<<dim3(DM_ / 128, ROWS / 64), 256, 0, stream>>>(
      avb, W1t, b1, base, t1, ROWS, DM_, DM_);
  normk<1><<<ROWS, 256, 0, stream>>>(t1, n1s, n1b, hidden, hbf);
  gemm64<2><<<dim3(DM_ / 128, ROWS / 64), 256, 0, stream>>>(
      hbf, W2t, b2, hidden, t1, ROWS, DM_, DM_);
  normk<0><<<ROWS, 256, 0, stream>>>(t1, n2s, n2b, out, nullptr);
}

// Round 7
// 266.134 us; speedup vs baseline: 1.0580x; 1.0580x over previous
//
#include <hip/hip_runtime.h>
#include <hip/hip_bf16.h>
#include <stdint.h>

#define B_ 4
#define S_ 2048
#define DM_ 768
#define H_ 12
#define HD_ 64
#define ROWS (B_*S_)      // 8192
#define QKVN (3*DM_)      // 2304

typedef __attribute__((ext_vector_type(8))) short short8;
typedef __attribute__((ext_vector_type(4))) float floatx4;
typedef __attribute__((ext_vector_type(8))) unsigned short ushort8;
typedef __attribute__((ext_vector_type(4))) unsigned short ushort4v;
typedef __attribute__((ext_vector_type(4))) float float4_t;

__device__ __forceinline__ unsigned short f2b(float f) {
  union { float f; uint32_t u; } x; x.f = f;
  uint32_t r = x.u + 0x7FFFu + ((x.u >> 16) & 1u);
  return (unsigned short)(r >> 16);
}
__device__ __forceinline__ uint32_t fbits(float f) {
  union { float f; uint32_t u; } x; x.f = f; return x.u;
}

// async global->LDS, 16B per lane. LDS dest is wave-uniform base + lane*16.
__device__ __forceinline__ void load_lds16(const void* g, void* l) {
  __builtin_amdgcn_global_load_lds(
      (const __attribute__((address_space(1))) uint32_t*)g,
      (__attribute__((address_space(3))) uint32_t*)l, 16, 0, 0);
}

// ---------------- fused prep: base cast + 3 weight transposes ----------------
// block ranges: [0,6144) cvt | [6144,7872) Wqkv | [7872,8448) W1 | [8448,9024) W2
#define CVT_B 6144
#define WQ_B 1728
#define W1_B 576
__global__ __launch_bounds__(256) void prep(
    const float* __restrict__ base, unsigned short* __restrict__ base_bf,
    const float* __restrict__ Wqkv, unsigned short* __restrict__ Wqkvt,
    const float* __restrict__ W1, unsigned short* __restrict__ W1t,
    const float* __restrict__ W2, unsigned short* __restrict__ W2t) {
  __shared__ float t[32][33];
  int bid = blockIdx.x;
  int tid = threadIdx.x;
  if (bid < CVT_B) {
    int i = bid * 256 + tid;
    float4_t v = ((const float4_t*)base)[i];
    ushort4v o;
    o[0] = f2b(v[0]); o[1] = f2b(v[1]); o[2] = f2b(v[2]); o[3] = f2b(v[3]);
    ((ushort4v*)base_bf)[i] = o;
    return;
  }
  const float* W; unsigned short* Wt; int N, rel;
  if (bid < CVT_B + WQ_B)      { W = Wqkv; Wt = Wqkvt; N = QKVN; rel = bid - CVT_B; }
  else if (bid < CVT_B + WQ_B + W1_B) { W = W1; Wt = W1t; N = DM_; rel = bid - CVT_B - WQ_B; }
  else                          { W = W2; Wt = W2t; N = DM_; rel = bid - CVT_B - WQ_B - W1_B; }
  int K = DM_;
  int n0 = (rel % (N / 32)) * 32, k0 = (rel / (N / 32)) * 32;
  int tx = tid & 31, ty = tid >> 5;  // ty 0..7
#pragma unroll
  for (int i = 0; i < 4; i++)
    t[ty + i * 8][tx] = W[(size_t)(k0 + ty + i * 8) * N + n0 + tx];
  __syncthreads();
#pragma unroll
  for (int i = 0; i < 4; i++)
    Wt[(size_t)(n0 + ty + i * 8) * K + k0 + tx] = f2b(t[tx][ty + i * 8]);
}

// ---------------- V slice of qkv -> Vt [b*H+h][d][s-tiles, permuted] bf16 ----------------
// within each 64-key tile, output position p holds key s = ((p&3)<<4)|(p>>2)
// (forward: key s lands at pos (s&15)*4 + (s>>4)) — matches attn's packed-P column order.
__global__ __launch_bounds__(256) void vtrans(const unsigned short* __restrict__ qkv,
                                              unsigned short* __restrict__ Vt) {
  int st = blockIdx.x;   // s-tile 0..31
  int bh = blockIdx.y;   // 0..47
  int b = bh / H_, h = bh % H_;
  __shared__ unsigned short t[64][65];
  int tid = threadIdx.x;
#pragma unroll
  for (int i = 0; i < 2; i++) {
    int c = i * 256 + tid;
    int r = c >> 3, o = (c & 7) * 8;
    ushort8 v = *(const ushort8*)(qkv + (size_t)(b * S_ + st * 64 + r) * QKVN + 2 * DM_ + h * HD_ + o);
#pragma unroll
    for (int j = 0; j < 8; j++) t[r][o + j] = v[j];
  }
  __syncthreads();
#pragma unroll
  for (int i = 0; i < 2; i++) {
    int c = i * 256 + tid;
    int d = c >> 3, o = (c & 7) * 8;
    ushort8 v;
#pragma unroll
    for (int j = 0; j < 8; j++) {
      int p = o + j;
      int s = ((p & 3) << 4) | (p >> 2);
      v[j] = t[s][d];
    }
    *(ushort8*)(Vt + (size_t)(bh * 64 + d) * S_ + st * 64 + o) = v;
  }
}

// ---------------- bf16 MFMA GEMM (128x128 tile): used for QKV ----------------
// XOR-swizzled LDS; EPI=0 additionally pre-scales Q columns (col<DM_) by
// 0.125*log2(e) so attn's softmax needs no per-score multiply.
template <int EPI>
__global__ __launch_bounds__(256, 2) void gemm_bf16(
    const unsigned short* __restrict__ A,
    const unsigned short* __restrict__ Bt,
    const float* __restrict__ bias,
    const float* __restrict__ res,
    void* __restrict__ Cout,
    int M, int N, int K) {
  __shared__ __align__(16) unsigned short As[128 * 64];
  __shared__ __align__(16) unsigned short Bs[128 * 64];
  int tid = threadIdx.x;
  int wave = tid >> 6, lane = tid & 63;
  int quad = lane >> 4, l16 = lane & 15;
  int e = l16 & 7;
  int sr = lane >> 3;                 // staging row within 8-row op
  int sc = (lane & 7) ^ (sr & 7);     // swizzled source chunk
  int m0 = blockIdx.y * 128, n0 = blockIdx.x * 128;
  int wm = (wave >> 1) * 64, wn = (wave & 1) * 64;
  floatx4 acc[4][4] = {};
  int c0 = wave * 4;

  for (int kb = 0; kb < K; kb += 64) {
#pragma unroll
    for (int i = 0; i < 4; i++) {
      int op = c0 + i;
      load_lds16(A + (size_t)(m0 + op * 8 + sr) * K + kb + sc * 8, (char*)As + op * 1024);
    }
#pragma unroll
    for (int i = 0; i < 4; i++) {
      int op = c0 + i;
      load_lds16(Bt + (size_t)(n0 + op * 8 + sr) * K + kb + sc * 8, (char*)Bs + op * 1024);
    }
    __syncthreads();  // drains vmcnt (global_load_lds) + barrier
#pragma unroll
    for (int ks = 0; ks < 2; ks++) {
      short8 af[4], bfr[4];
#pragma unroll
      for (int mt = 0; mt < 4; mt++)
        af[mt] = *(const short8*)(As + (wm + mt * 16 + l16) * 64 + ((ks * 4 + quad) ^ e) * 8);
#pragma unroll
      for (int nt = 0; nt < 4; nt++)
        bfr[nt] = *(const short8*)(Bs + (wn + nt * 16 + l16) * 64 + ((ks * 4 + quad) ^ e) * 8);
#pragma unroll
      for (int mt = 0; mt < 4; mt++)
#pragma unroll
        for (int nt = 0; nt < 4; nt++)
          acc[mt][nt] = __builtin_amdgcn_mfma_f32_16x16x32_bf16(af[mt], bfr[nt], acc[mt][nt], 0, 0, 0);
    }
    __syncthreads();
  }
#pragma unroll
  for (int mt = 0; mt < 4; mt++) {
#pragma unroll
    for (int nt = 0; nt < 4; nt++) {
#pragma unroll
      for (int r = 0; r < 4; r++) {
        int row = m0 + wm + mt * 16 + quad * 4 + r;
        int col = n0 + wn + nt * 16 + l16;
        size_t idx = (size_t)row * N + col;
        float v = acc[mt][nt][r] + bias[col];
        if (EPI == 0) {
          if (col < DM_) v *= 0.18033688011112042f;  // 0.125*log2(e): pre-scale Q
          ((unsigned short*)Cout)[idx] = f2b(v);
        } else if (EPI == 1) {
          ((float*)Cout)[idx] = v + res[idx];
        } else {
          ((float*)Cout)[idx] = fmaxf(v, 0.0f) + res[idx];
        }
      }
    }
  }
}

// ---------------- bf16 MFMA GEMM (64x128 tile, 4 blocks/CU): for N=768 GEMMs ----------------
// 768 blocks -> balanced 3/CU single round. Same swizzle scheme as gemm_bf16.
template <int EPI>
__global__ __launch_bounds__(256, 4) void gemm64(
    const unsigned short* __restrict__ A,
    const unsigned short* __restrict__ Bt,
    const float* __restrict__ bias,
    const float* __restrict__ res,
    void* __restrict__ Cout,
    int M, int N, int K) {
  __shared__ __align__(16) unsigned short As[64 * 64];
  __shared__ __align__(16) unsigned short Bs[128 * 64];
  int tid = threadIdx.x;
  int wave = tid >> 6, lane = tid & 63;
  int quad = lane >> 4, l16 = lane & 15;
  int e = l16 & 7;
  int sr = lane >> 3;
  int sc = (lane & 7) ^ (sr & 7);
  int m0 = blockIdx.y * 64, n0 = blockIdx.x * 128;
  int wm = (wave >> 1) * 32, wn = (wave & 1) * 64;
  floatx4 acc[2][4] = {};

  for (int kb = 0; kb < K; kb += 64) {
#pragma unroll
    for (int i = 0; i < 2; i++) {
      int op = wave * 2 + i;  // 8 A ops
      load_lds16(A + (size_t)(m0 + op * 8 + sr) * K + kb + sc * 8, (char*)As + op * 1024);
    }
#pragma unroll
    for (int i = 0; i < 4; i++) {
      int op = wave * 4 + i;  // 16 B ops
      load_lds16(Bt + (size_t)(n0 + op * 8 + sr) * K + kb + sc * 8, (char*)Bs + op * 1024);
    }
    __syncthreads();
#pragma unroll
    for (int ks = 0; ks < 2; ks++) {
      short8 af[2], bfr[4];
#pragma unroll
      for (int mt = 0; mt < 2; mt++)
        af[mt] = *(const short8*)(As + (wm + mt * 16 + l16) * 64 + ((ks * 4 + quad) ^ e) * 8);
#pragma unroll
      for (int nt = 0; nt < 4; nt++)
        bfr[nt] = *(const short8*)(Bs + (wn + nt * 16 + l16) * 64 + ((ks * 4 + quad) ^ e) * 8);
#pragma unroll
      for (int mt = 0; mt < 2; mt++)
#pragma unroll
        for (int nt = 0; nt < 4; nt++)
          acc[mt][nt] = __builtin_amdgcn_mfma_f32_16x16x32_bf16(af[mt], bfr[nt], acc[mt][nt], 0, 0, 0);
    }
    __syncthreads();
  }
#pragma unroll
  for (int mt = 0; mt < 2; mt++) {
#pragma unroll
    for (int nt = 0; nt < 4; nt++) {
#pragma unroll
      for (int r = 0; r < 4; r++) {
        int row = m0 + wm + mt * 16 + quad * 4 + r;
        int col = n0 + wn + nt * 16 + l16;
        size_t idx = (size_t)row * N + col;
        float v = acc[mt][nt][r] + bias[col];
        if (EPI == 0) {
          ((unsigned short*)Cout)[idx] = f2b(v);
        } else if (EPI == 1) {
          ((float*)Cout)[idx] = v + res[idx];
        } else {
          ((float*)Cout)[idx] = fmaxf(v, 0.0f) + res[idx];
        }
      }
    }
  }
}

// ---------------- flash attention: av = softmax(Q K^T / 8) V ----------------
// 4 waves x 32 q-rows (R5 config: 12 waves/CU). Q pre-scaled by 0.125*log2(e) in the
// QKV GEMM, so p = exp2(sv) directly. Staging addresses strength-reduced to pointer
// increments. Q staged into each wave's private Ps slab (read once into regs, space
// reused for P). XOR-swizzled Ks/Vs; P packed 4-wide (permuted key order matching Vt)
// via v_perm -> ds_write_b64; no running max; denominator via MFMA with ones.
__global__ __launch_bounds__(256, 2) void attn(
    const unsigned short* __restrict__ qkv,
    const unsigned short* __restrict__ Vt,
    unsigned short* __restrict__ av) {
  int qt = blockIdx.x;   // q-tile 0..15 (128 rows)
  int bh = blockIdx.y;   // 0..47
  int b = bh / H_, h = bh % H_;
  int row0 = b * S_ + qt * 128;
  __shared__ __align__(16) unsigned short Ks[2][64 * 64];
  __shared__ __align__(16) unsigned short Vs[2][64 * 64];
  __shared__ __align__(16) unsigned short Ps[4][32 * 72];  // row stride 144B; doubles as Q staging
  int tid = threadIdx.x;
  int wave = tid >> 6, lane = tid & 63;
  int quad = lane >> 4, l16 = lane & 15;
  int e = l16 & 7;
  int sr = lane >> 3;
  int sc = (lane & 7) ^ (sr & 7);

  // stage this wave's 32 Q rows into its own Ps slab (row stride 128B, swizzled chunks)
#pragma unroll
  for (int i = 0; i < 4; i++) {
    load_lds16(qkv + (size_t)(row0 + wave * 32 + i * 8 + sr) * QKVN + h * HD_ + sc * 8,
               (char*)Ps[wave] + i * 1024);
  }
  // lane-constant staging pointers; advanced by fixed strides per K-tile
  const unsigned short* kp = qkv + (size_t)(b * S_ + wave * 16 + sr) * QKVN + DM_ + h * HD_ + sc * 8;
  const unsigned short* vp = Vt + ((size_t)bh * 64 + wave * 16 + sr) * S_ + sc * 8;
  auto stageKV = [&](const unsigned short* kq, const unsigned short* vq, int buf) {
#pragma unroll
    for (int i = 0; i < 2; i++) {
      load_lds16(kq + (size_t)i * 8 * QKVN, (char*)Ks[buf] + wave * 2048 + i * 1024);
      load_lds16(vq + (size_t)i * 8 * S_, (char*)Vs[buf] + wave * 2048 + i * 1024);
    }
  };
  stageKV(kp, vp, 0);

  floatx4 accO[2][4] = {};
  floatx4 accL[2] = {};
  short8 ones;
#pragma unroll
  for (int j = 0; j < 8; j++) ones[j] = (short)0x3F80;  // bf16 1.0
  __syncthreads();  // Q + KV(0) staged (drains vmcnt)

  // hoist Q fragments from this wave's Ps slab (before any P write; same-wave ordering)
  short8 qf[2][2];
#pragma unroll
  for (int mf = 0; mf < 2; mf++)
#pragma unroll
    for (int ks = 0; ks < 2; ks++)
      qf[mf][ks] = *(const short8*)(Ps[wave] + (mf * 16 + l16) * 64 + ((ks * 4 + quad) ^ e) * 8);

  int cur = 0;
  for (int kt = 0; kt < 32; kt++) {
    floatx4 sv[2][4] = {};
#pragma unroll
    for (int ks = 0; ks < 2; ks++)
#pragma unroll
      for (int nt = 0; nt < 4; nt++) {
        short8 kf = *(const short8*)(Ks[cur] + (nt * 16 + l16) * 64 + ((ks * 4 + quad) ^ e) * 8);
#pragma unroll
        for (int mf = 0; mf < 2; mf++)
          sv[mf][nt] = __builtin_amdgcn_mfma_f32_16x16x32_bf16(qf[mf][ks], kf, sv[mf][nt], 0, 0, 0);
      }
    // prefetch next K/V now: overlaps softmax + PV below
    if (kt + 1 < 32) {
      kp += 64 * QKVN;
      vp += 64;
      stageKV(kp, vp, cur ^ 1);
    }
    // p = exp2(sv) (scale folded into Q); pack 4 bf16 -> b64 write
#pragma unroll
    for (int mf = 0; mf < 2; mf++)
#pragma unroll
      for (int r = 0; r < 4; r++) {
        uint32_t u0 = fbits(__builtin_amdgcn_exp2f(sv[mf][0][r]));
        uint32_t u1 = fbits(__builtin_amdgcn_exp2f(sv[mf][1][r]));
        uint32_t u2 = fbits(__builtin_amdgcn_exp2f(sv[mf][2][r]));
        uint32_t u3 = fbits(__builtin_amdgcn_exp2f(sv[mf][3][r]));
        uint2 val;
        val.x = __builtin_amdgcn_perm(u1, u0, 0x07060302u);  // [u0.hi16, u1.hi16]
        val.y = __builtin_amdgcn_perm(u3, u2, 0x07060302u);  // [u2.hi16, u3.hi16]
        *(uint2*)(&Ps[wave][(mf * 16 + quad * 4 + r) * 72 + l16 * 4]) = val;
      }
#pragma unroll
    for (int ks = 0; ks < 2; ks++) {
      short8 pf[2];
#pragma unroll
      for (int mf = 0; mf < 2; mf++) {
        pf[mf] = *(const short8*)(Ps[wave] + (mf * 16 + l16) * 72 + ks * 32 + quad * 8);
        accL[mf] = __builtin_amdgcn_mfma_f32_16x16x32_bf16(pf[mf], ones, accL[mf], 0, 0, 0);
      }
#pragma unroll
      for (int nt = 0; nt < 4; nt++) {
        short8 vf = *(const short8*)(Vs[cur] + (nt * 16 + l16) * 64 + ((ks * 4 + quad) ^ e) * 8);
#pragma unroll
        for (int mf = 0; mf < 2; mf++)
          accO[mf][nt] = __builtin_amdgcn_mfma_f32_16x16x32_bf16(pf[mf], vf, accO[mf][nt], 0, 0, 0);
      }
    }
    __syncthreads();  // drains prefetch vmcnt; all waves done with cur
    cur ^= 1;
  }
#pragma unroll
  for (int mf = 0; mf < 2; mf++)
#pragma unroll
    for (int r = 0; r < 4; r++) {
      float inv = 1.0f / accL[mf][r];
      int row = row0 + wave * 32 + mf * 16 + quad * 4 + r;
#pragma unroll
      for (int nt = 0; nt < 4; nt++)
        av[(size_t)row * DM_ + h * HD_ + nt * 16 + l16] = f2b(accO[mf][nt][r] * inv);
    }
}

// ---------------- row norm: (x-mean)/std * scale + bias ----------------
template <int WB>
__global__ __launch_bounds__(256) void normk(
    const float* __restrict__ X, const float* __restrict__ scale,
    const float* __restrict__ bias, float* __restrict__ Y,
    unsigned short* __restrict__ Ybf) {
  int row = blockIdx.x;
  const float* x = X + (size_t)row * DM_;
  int tid = threadIdx.x;
  int wave = tid >> 6, lane = tid & 63;
  float v[3];
#pragma unroll
  for (int i = 0; i < 3; i++) v[i] = x[tid + i * 256];
  float s = v[0] + v[1] + v[2];
#pragma unroll
  for (int o = 32; o > 0; o >>= 1) s += __shfl_xor(s, o);
  __shared__ float red[4];
  if (lane == 0) red[wave] = s;
  __syncthreads();
  float mean = (red[0] + red[1] + red[2] + red[3]) * (1.0f / DM_);
  float ss = 0.0f;
#pragma unroll
  for (int i = 0; i < 3; i++) { v[i] -= mean; ss += v[i] * v[i]; }
#pragma unroll
  for (int o = 32; o > 0; o >>= 1) ss += __shfl_xor(ss, o);
  __syncthreads();
  if (lane == 0) red[wave] = ss;
  __syncthreads();
  float var = (red[0] + red[1] + red[2] + red[3]) * (1.0f / DM_);
  float rstd = rsqrtf(var);
  float sg = scale[0], bg = bias[0];
#pragma unroll
  for (int i = 0; i < 3; i++) {
    float y = v[i] * rstd * sg + bg;
    Y[(size_t)row * DM_ + tid + i * 256] = y;
    if (WB) Ybf[(size_t)row * DM_ + tid + i * 256] = f2b(y);
  }
}

extern "C" void kernel_launch(void* const* d_in, const int* in_sizes, int n_in,
                              void* d_out, int out_size, void* d_ws, size_t ws_size,
                              hipStream_t stream) {
  const float* base = (const float*)d_in[0];
  const float* Wqkv = (const float*)d_in[1];
  const float* bqkv = (const float*)d_in[2];
  const float* W1 = (const float*)d_in[3];
  const float* b1 = (const float*)d_in[4];
  const float* W2 = (const float*)d_in[5];
  const float* b2 = (const float*)d_in[6];
  const float* n1s = (const float*)d_in[7];
  const float* n1b = (const float*)d_in[8];
  const float* n2s = (const float*)d_in[9];
  const float* n2b = (const float*)d_in[10];
  float* out = (float*)d_out;

  char* ws = (char*)d_ws;
  size_t off = 0;
  auto alloc = [&](size_t bytes) {
    char* p = ws + off;
    off = (off + bytes + 255) & ~(size_t)255;
    return p;
  };
  unsigned short* base_bf = (unsigned short*)alloc((size_t)ROWS * DM_ * 2);
  unsigned short* Wqkvt = (unsigned short*)alloc((size_t)QKVN * DM_ * 2);
  unsigned short* W1t = (unsigned short*)alloc((size_t)DM_ * DM_ * 2);
  unsigned short* W2t = (unsigned short*)alloc((size_t)DM_ * DM_ * 2);
  unsigned short* qkvb = (unsigned short*)alloc((size_t)ROWS * QKVN * 2);
  unsigned short* Vtb = (unsigned short*)alloc((size_t)B_ * H_ * HD_ * S_ * 2);
  unsigned short* avb = (unsigned short*)alloc((size_t)ROWS * DM_ * 2);
  float* t1 = (float*)alloc((size_t)ROWS * DM_ * 4);        // reused for t2
  float* hidden = (float*)alloc((size_t)ROWS * DM_ * 4);
  unsigned short* hbf = (unsigned short*)alloc((size_t)ROWS * DM_ * 2);

  prep<<<CVT_B + WQ_B + 2 * W1_B, 256, 0, stream>>>(
      base, base_bf, Wqkv, Wqkvt, W1, W1t, W2, W2t);
  gemm_bf16<0><<<dim3(QKVN / 128, ROWS / 128), 256, 0, stream>>>(
      base_bf, Wqkvt, bqkv, nullptr, qkvb, ROWS, QKVN, DM_);
  vtrans<<<dim3(S_ / 64, B_ * H_), 256, 0, stream>>>(qkvb, Vtb);
  attn<<<dim3(S_ / 128, B_ * H_), 256, 0, stream>>>(qkvb, Vtb, avb);
  gemm64<1><<<dim3(DM_ / 128, ROWS / 64), 256, 0, stream>>>(
      avb, W1t, b1, base, t1, ROWS, DM_, DM_);
  normk<1><<<ROWS, 256, 0, stream>>>(t1, n1s, n1b, hidden, hbf);
  gemm64<2><<<dim3(DM_ / 128, ROWS / 64), 256, 0, stream>>>(
      hbf, W2t, b2, hidden, t1, ROWS, DM_, DM_);
  normk<0><<<ROWS, 256, 0, stream>>>(t1, n2s, n2b, out, nullptr);
}

// Round 8
// 258.158 us; speedup vs baseline: 1.0907x; 1.0309x over previous
//
#include <hip/hip_runtime.h>
#include <hip/hip_bf16.h>
#include <stdint.h>

#define B_ 4
#define S_ 2048
#define DM_ 768
#define H_ 12
#define HD_ 64
#define ROWS (B_*S_)      // 8192
#define QKVN (3*DM_)      // 2304

typedef __attribute__((ext_vector_type(8))) short short8;
typedef __attribute__((ext_vector_type(4))) float floatx4;
typedef __attribute__((ext_vector_type(8))) unsigned short ushort8;
typedef __attribute__((ext_vector_type(4))) unsigned short ushort4v;
typedef __attribute__((ext_vector_type(4))) float float4_t;

__device__ __forceinline__ unsigned short f2b(float f) {
  union { float f; uint32_t u; } x; x.f = f;
  uint32_t r = x.u + 0x7FFFu + ((x.u >> 16) & 1u);
  return (unsigned short)(r >> 16);
}
__device__ __forceinline__ float b2f(unsigned short u) {
  union { uint32_t u; float f; } x; x.u = ((uint32_t)u) << 16; return x.f;
}
__device__ __forceinline__ uint32_t fbits(float f) {
  union { float f; uint32_t u; } x; x.f = f; return x.u;
}

// async global->LDS, 16B per lane. LDS dest is wave-uniform base + lane*16.
__device__ __forceinline__ void load_lds16(const void* g, void* l) {
  __builtin_amdgcn_global_load_lds(
      (const __attribute__((address_space(1))) uint32_t*)g,
      (__attribute__((address_space(3))) uint32_t*)l, 16, 0, 0);
}

// ---------------- fused prep: base cast + 3 weight transposes ----------------
// block ranges: [0,6144) cvt | [6144,7872) Wqkv | [7872,8448) W1 | [8448,9024) W2
#define CVT_B 6144
#define WQ_B 1728
#define W1_B 576
__global__ __launch_bounds__(256) void prep(
    const float* __restrict__ base, unsigned short* __restrict__ base_bf,
    const float* __restrict__ Wqkv, unsigned short* __restrict__ Wqkvt,
    const float* __restrict__ W1, unsigned short* __restrict__ W1t,
    const float* __restrict__ W2, unsigned short* __restrict__ W2t) {
  __shared__ float t[32][33];
  int bid = blockIdx.x;
  int tid = threadIdx.x;
  if (bid < CVT_B) {
    int i = bid * 256 + tid;
    float4_t v = ((const float4_t*)base)[i];
    ushort4v o;
    o[0] = f2b(v[0]); o[1] = f2b(v[1]); o[2] = f2b(v[2]); o[3] = f2b(v[3]);
    ((ushort4v*)base_bf)[i] = o;
    return;
  }
  const float* W; unsigned short* Wt; int N, rel;
  if (bid < CVT_B + WQ_B)      { W = Wqkv; Wt = Wqkvt; N = QKVN; rel = bid - CVT_B; }
  else if (bid < CVT_B + WQ_B + W1_B) { W = W1; Wt = W1t; N = DM_; rel = bid - CVT_B - WQ_B; }
  else                          { W = W2; Wt = W2t; N = DM_; rel = bid - CVT_B - WQ_B - W1_B; }
  int K = DM_;
  int n0 = (rel % (N / 32)) * 32, k0 = (rel / (N / 32)) * 32;
  int tx = tid & 31, ty = tid >> 5;  // ty 0..7
#pragma unroll
  for (int i = 0; i < 4; i++)
    t[ty + i * 8][tx] = W[(size_t)(k0 + ty + i * 8) * N + n0 + tx];
  __syncthreads();
#pragma unroll
  for (int i = 0; i < 4; i++)
    Wt[(size_t)(n0 + ty + i * 8) * K + k0 + tx] = f2b(t[tx][ty + i * 8]);
}

// ---------------- V slice of qkv -> Vt [b*H+h][d][s-tiles, permuted] bf16 ----------------
// within each 64-key tile, output position p holds key s = ((p&3)<<4)|(p>>2)
// (forward: key s lands at pos (s&15)*4 + (s>>4)) — matches attn's packed-P column order.
__global__ __launch_bounds__(256) void vtrans(const unsigned short* __restrict__ qkv,
                                              unsigned short* __restrict__ Vt) {
  int st = blockIdx.x;   // s-tile 0..31
  int bh = blockIdx.y;   // 0..47
  int b = bh / H_, h = bh % H_;
  __shared__ unsigned short t[64][65];
  int tid = threadIdx.x;
#pragma unroll
  for (int i = 0; i < 2; i++) {
    int c = i * 256 + tid;
    int r = c >> 3, o = (c & 7) * 8;
    ushort8 v = *(const ushort8*)(qkv + (size_t)(b * S_ + st * 64 + r) * QKVN + 2 * DM_ + h * HD_ + o);
#pragma unroll
    for (int j = 0; j < 8; j++) t[r][o + j] = v[j];
  }
  __syncthreads();
#pragma unroll
  for (int i = 0; i < 2; i++) {
    int c = i * 256 + tid;
    int d = c >> 3, o = (c & 7) * 8;
    ushort8 v;
#pragma unroll
    for (int j = 0; j < 8; j++) {
      int p = o + j;
      int s = ((p & 3) << 4) | (p >> 2);
      v[j] = t[s][d];
    }
    *(ushort8*)(Vt + (size_t)(bh * 64 + d) * S_ + st * 64 + o) = v;
  }
}

// ---------------- bf16 MFMA GEMM (128x128 tile): used for QKV ----------------
// XOR-swizzled LDS; epilogue pre-scales Q columns (col<DM_) by 0.125*log2(e)
// so attn's softmax needs no per-score multiply.
__global__ __launch_bounds__(256, 2) void gemm_qkv(
    const unsigned short* __restrict__ A,
    const unsigned short* __restrict__ Bt,
    const float* __restrict__ bias,
    unsigned short* __restrict__ Cout,
    int M, int N, int K) {
  __shared__ __align__(16) unsigned short As[128 * 64];
  __shared__ __align__(16) unsigned short Bs[128 * 64];
  int tid = threadIdx.x;
  int wave = tid >> 6, lane = tid & 63;
  int quad = lane >> 4, l16 = lane & 15;
  int e = l16 & 7;
  int sr = lane >> 3;                 // staging row within 8-row op
  int sc = (lane & 7) ^ (sr & 7);     // swizzled source chunk
  int m0 = blockIdx.y * 128, n0 = blockIdx.x * 128;
  int wm = (wave >> 1) * 64, wn = (wave & 1) * 64;
  floatx4 acc[4][4] = {};
  int c0 = wave * 4;

  for (int kb = 0; kb < K; kb += 64) {
#pragma unroll
    for (int i = 0; i < 4; i++) {
      int op = c0 + i;
      load_lds16(A + (size_t)(m0 + op * 8 + sr) * K + kb + sc * 8, (char*)As + op * 1024);
    }
#pragma unroll
    for (int i = 0; i < 4; i++) {
      int op = c0 + i;
      load_lds16(Bt + (size_t)(n0 + op * 8 + sr) * K + kb + sc * 8, (char*)Bs + op * 1024);
    }
    __syncthreads();  // drains vmcnt (global_load_lds) + barrier
#pragma unroll
    for (int ks = 0; ks < 2; ks++) {
      short8 af[4], bfr[4];
#pragma unroll
      for (int mt = 0; mt < 4; mt++)
        af[mt] = *(const short8*)(As + (wm + mt * 16 + l16) * 64 + ((ks * 4 + quad) ^ e) * 8);
#pragma unroll
      for (int nt = 0; nt < 4; nt++)
        bfr[nt] = *(const short8*)(Bs + (wn + nt * 16 + l16) * 64 + ((ks * 4 + quad) ^ e) * 8);
#pragma unroll
      for (int mt = 0; mt < 4; mt++)
#pragma unroll
        for (int nt = 0; nt < 4; nt++)
          acc[mt][nt] = __builtin_amdgcn_mfma_f32_16x16x32_bf16(af[mt], bfr[nt], acc[mt][nt], 0, 0, 0);
    }
    __syncthreads();
  }
#pragma unroll
  for (int mt = 0; mt < 4; mt++) {
#pragma unroll
    for (int nt = 0; nt < 4; nt++) {
#pragma unroll
      for (int r = 0; r < 4; r++) {
        int row = m0 + wm + mt * 16 + quad * 4 + r;
        int col = n0 + wn + nt * 16 + l16;
        size_t idx = (size_t)row * N + col;
        float v = acc[mt][nt][r] + bias[col];
        if (col < DM_) v *= 0.18033688011112042f;  // 0.125*log2(e): pre-scale Q
        Cout[idx] = f2b(v);
      }
    }
  }
}

// ---------------- bf16 MFMA GEMM (64x128 tile, 4 blocks/CU): MLP GEMMs ----------------
// EPI=1: bias + res(bf16) -> bf16 out. EPI=2: relu(bias) + res(bf16) -> bf16 out.
// All intermediates bf16 to cut HBM traffic ~4x on this chain.
template <int EPI>
__global__ __launch_bounds__(256, 4) void gemm64(
    const unsigned short* __restrict__ A,
    const unsigned short* __restrict__ Bt,
    const float* __restrict__ bias,
    const unsigned short* __restrict__ res,
    unsigned short* __restrict__ Cout,
    int M, int N, int K) {
  __shared__ __align__(16) unsigned short As[64 * 64];
  __shared__ __align__(16) unsigned short Bs[128 * 64];
  int tid = threadIdx.x;
  int wave = tid >> 6, lane = tid & 63;
  int quad = lane >> 4, l16 = lane & 15;
  int e = l16 & 7;
  int sr = lane >> 3;
  int sc = (lane & 7) ^ (sr & 7);
  int m0 = blockIdx.y * 64, n0 = blockIdx.x * 128;
  int wm = (wave >> 1) * 32, wn = (wave & 1) * 64;
  floatx4 acc[2][4] = {};

  for (int kb = 0; kb < K; kb += 64) {
#pragma unroll
    for (int i = 0; i < 2; i++) {
      int op = wave * 2 + i;  // 8 A ops
      load_lds16(A + (size_t)(m0 + op * 8 + sr) * K + kb + sc * 8, (char*)As + op * 1024);
    }
#pragma unroll
    for (int i = 0; i < 4; i++) {
      int op = wave * 4 + i;  // 16 B ops
      load_lds16(Bt + (size_t)(n0 + op * 8 + sr) * K + kb + sc * 8, (char*)Bs + op * 1024);
    }
    __syncthreads();
#pragma unroll
    for (int ks = 0; ks < 2; ks++) {
      short8 af[2], bfr[4];
#pragma unroll
      for (int mt = 0; mt < 2; mt++)
        af[mt] = *(const short8*)(As + (wm + mt * 16 + l16) * 64 + ((ks * 4 + quad) ^ e) * 8);
#pragma unroll
      for (int nt = 0; nt < 4; nt++)
        bfr[nt] = *(const short8*)(Bs + (wn + nt * 16 + l16) * 64 + ((ks * 4 + quad) ^ e) * 8);
#pragma unroll
      for (int mt = 0; mt < 2; mt++)
#pragma unroll
        for (int nt = 0; nt < 4; nt++)
          acc[mt][nt] = __builtin_amdgcn_mfma_f32_16x16x32_bf16(af[mt], bfr[nt], acc[mt][nt], 0, 0, 0);
    }
    __syncthreads();
  }
#pragma unroll
  for (int mt = 0; mt < 2; mt++) {
#pragma unroll
    for (int nt = 0; nt < 4; nt++) {
#pragma unroll
      for (int r = 0; r < 4; r++) {
        int row = m0 + wm + mt * 16 + quad * 4 + r;
        int col = n0 + wn + nt * 16 + l16;
        size_t idx = (size_t)row * N + col;
        float v = acc[mt][nt][r] + bias[col];
        if (EPI == 2) v = fmaxf(v, 0.0f);
        v += b2f(res[idx]);
        Cout[idx] = f2b(v);
      }
    }
  }
}

// ---------------- flash attention: av = softmax(Q K^T / 8) V ----------------
// 4 waves x 32 q-rows (12 waves/CU). Q pre-scaled by 0.125*log2(e) in the QKV GEMM,
// so p = exp2(sv) directly. Staging addresses strength-reduced to pointer increments.
// Q staged into each wave's private Ps slab (read once into regs, space reused for P).
// XOR-swizzled Ks/Vs; P packed 4-wide (permuted key order matching Vt) via v_perm ->
// ds_write_b64; no running max; denominator via MFMA with ones.
__global__ __launch_bounds__(256, 2) void attn(
    const unsigned short* __restrict__ qkv,
    const unsigned short* __restrict__ Vt,
    unsigned short* __restrict__ av) {
  int qt = blockIdx.x;   // q-tile 0..15 (128 rows)
  int bh = blockIdx.y;   // 0..47
  int b = bh / H_, h = bh % H_;
  int row0 = b * S_ + qt * 128;
  __shared__ __align__(16) unsigned short Ks[2][64 * 64];
  __shared__ __align__(16) unsigned short Vs[2][64 * 64];
  __shared__ __align__(16) unsigned short Ps[4][32 * 72];  // row stride 144B; doubles as Q staging
  int tid = threadIdx.x;
  int wave = tid >> 6, lane = tid & 63;
  int quad = lane >> 4, l16 = lane & 15;
  int e = l16 & 7;
  int sr = lane >> 3;
  int sc = (lane & 7) ^ (sr & 7);

  // stage this wave's 32 Q rows into its own Ps slab (row stride 128B, swizzled chunks)
#pragma unroll
  for (int i = 0; i < 4; i++) {
    load_lds16(qkv + (size_t)(row0 + wave * 32 + i * 8 + sr) * QKVN + h * HD_ + sc * 8,
               (char*)Ps[wave] + i * 1024);
  }
  // lane-constant staging pointers; advanced by fixed strides per K-tile
  const unsigned short* kp = qkv + (size_t)(b * S_ + wave * 16 + sr) * QKVN + DM_ + h * HD_ + sc * 8;
  const unsigned short* vp = Vt + ((size_t)bh * 64 + wave * 16 + sr) * S_ + sc * 8;
  auto stageKV = [&](const unsigned short* kq, const unsigned short* vq, int buf) {
#pragma unroll
    for (int i = 0; i < 2; i++) {
      load_lds16(kq + (size_t)i * 8 * QKVN, (char*)Ks[buf] + wave * 2048 + i * 1024);
      load_lds16(vq + (size_t)i * 8 * S_, (char*)Vs[buf] + wave * 2048 + i * 1024);
    }
  };
  stageKV(kp, vp, 0);

  floatx4 accO[2][4] = {};
  floatx4 accL[2] = {};
  short8 ones;
#pragma unroll
  for (int j = 0; j < 8; j++) ones[j] = (short)0x3F80;  // bf16 1.0
  __syncthreads();  // Q + KV(0) staged (drains vmcnt)

  // hoist Q fragments from this wave's Ps slab (before any P write; same-wave ordering)
  short8 qf[2][2];
#pragma unroll
  for (int mf = 0; mf < 2; mf++)
#pragma unroll
    for (int ks = 0; ks < 2; ks++)
      qf[mf][ks] = *(const short8*)(Ps[wave] + (mf * 16 + l16) * 64 + ((ks * 4 + quad) ^ e) * 8);

  int cur = 0;
  for (int kt = 0; kt < 32; kt++) {
    floatx4 sv[2][4] = {};
#pragma unroll
    for (int ks = 0; ks < 2; ks++)
#pragma unroll
      for (int nt = 0; nt < 4; nt++) {
        short8 kf = *(const short8*)(Ks[cur] + (nt * 16 + l16) * 64 + ((ks * 4 + quad) ^ e) * 8);
#pragma unroll
        for (int mf = 0; mf < 2; mf++)
          sv[mf][nt] = __builtin_amdgcn_mfma_f32_16x16x32_bf16(qf[mf][ks], kf, sv[mf][nt], 0, 0, 0);
      }
    // prefetch next K/V now: overlaps softmax + PV below
    if (kt + 1 < 32) {
      kp += 64 * QKVN;
      vp += 64;
      stageKV(kp, vp, cur ^ 1);
    }
    // p = exp2(sv) (scale folded into Q); pack 4 bf16 -> b64 write
#pragma unroll
    for (int mf = 0; mf < 2; mf++)
#pragma unroll
      for (int r = 0; r < 4; r++) {
        uint32_t u0 = fbits(__builtin_amdgcn_exp2f(sv[mf][0][r]));
        uint32_t u1 = fbits(__builtin_amdgcn_exp2f(sv[mf][1][r]));
        uint32_t u2 = fbits(__builtin_amdgcn_exp2f(sv[mf][2][r]));
        uint32_t u3 = fbits(__builtin_amdgcn_exp2f(sv[mf][3][r]));
        uint2 val;
        val.x = __builtin_amdgcn_perm(u1, u0, 0x07060302u);  // [u0.hi16, u1.hi16]
        val.y = __builtin_amdgcn_perm(u3, u2, 0x07060302u);  // [u2.hi16, u3.hi16]
        *(uint2*)(&Ps[wave][(mf * 16 + quad * 4 + r) * 72 + l16 * 4]) = val;
      }
#pragma unroll
    for (int ks = 0; ks < 2; ks++) {
      short8 pf[2];
#pragma unroll
      for (int mf = 0; mf < 2; mf++) {
        pf[mf] = *(const short8*)(Ps[wave] + (mf * 16 + l16) * 72 + ks * 32 + quad * 8);
        accL[mf] = __builtin_amdgcn_mfma_f32_16x16x32_bf16(pf[mf], ones, accL[mf], 0, 0, 0);
      }
#pragma unroll
      for (int nt = 0; nt < 4; nt++) {
        short8 vf = *(const short8*)(Vs[cur] + (nt * 16 + l16) * 64 + ((ks * 4 + quad) ^ e) * 8);
#pragma unroll
        for (int mf = 0; mf < 2; mf++)
          accO[mf][nt] = __builtin_amdgcn_mfma_f32_16x16x32_bf16(pf[mf], vf, accO[mf][nt], 0, 0, 0);
      }
    }
    __syncthreads();  // drains prefetch vmcnt; all waves done with cur
    cur ^= 1;
  }
#pragma unroll
  for (int mf = 0; mf < 2; mf++)
#pragma unroll
    for (int r = 0; r < 4; r++) {
      float inv = 1.0f / accL[mf][r];
      int row = row0 + wave * 32 + mf * 16 + quad * 4 + r;
#pragma unroll
      for (int nt = 0; nt < 4; nt++)
        av[(size_t)row * DM_ + h * HD_ + nt * 16 + l16] = f2b(accO[mf][nt][r] * inv);
    }
}

// ---------------- row norm: (x-mean)/std * scale + bias (bf16 input) ----------------
// WB=1: write bf16 only. WB=0: write f32 only (final output).
template <int WB>
__global__ __launch_bounds__(256) void normk(
    const unsigned short* __restrict__ X, const float* __restrict__ scale,
    const float* __restrict__ bias, float* __restrict__ Y,
    unsigned short* __restrict__ Ybf) {
  int row = blockIdx.x;
  const unsigned short* x = X + (size_t)row * DM_;
  int tid = threadIdx.x;
  int wave = tid >> 6, lane = tid & 63;
  float v[3];
#pragma unroll
  for (int i = 0; i < 3; i++) v[i] = b2f(x[tid + i * 256]);
  float s = v[0] + v[1] + v[2];
#pragma unroll
  for (int o = 32; o > 0; o >>= 1) s += __shfl_xor(s, o);
  __shared__ float red[4];
  if (lane == 0) red[wave] = s;
  __syncthreads();
  float mean = (red[0] + red[1] + red[2] + red[3]) * (1.0f / DM_);
  float ss = 0.0f;
#pragma unroll
  for (int i = 0; i < 3; i++) { v[i] -= mean; ss += v[i] * v[i]; }
#pragma unroll
  for (int o = 32; o > 0; o >>= 1) ss += __shfl_xor(ss, o);
  __syncthreads();
  if (lane == 0) red[wave] = ss;
  __syncthreads();
  float var = (red[0] + red[1] + red[2] + red[3]) * (1.0f / DM_);
  float rstd = rsqrtf(var);
  float sg = scale[0], bg = bias[0];
#pragma unroll
  for (int i = 0; i < 3; i++) {
    float y = v[i] * rstd * sg + bg;
    if (WB) Ybf[(size_t)row * DM_ + tid + i * 256] = f2b(y);
    else    Y[(size_t)row * DM_ + tid + i * 256] = y;
  }
}

extern "C" void kernel_launch(void* const* d_in, const int* in_sizes, int n_in,
                              void* d_out, int out_size, void* d_ws, size_t ws_size,
                              hipStream_t stream) {
  const float* base = (const float*)d_in[0];
  const float* Wqkv = (const float*)d_in[1];
  const float* bqkv = (const float*)d_in[2];
  const float* W1 = (const float*)d_in[3];
  const float* b1 = (const float*)d_in[4];
  const float* W2 = (const float*)d_in[5];
  const float* b2 = (const float*)d_in[6];
  const float* n1s = (const float*)d_in[7];
  const float* n1b = (const float*)d_in[8];
  const float* n2s = (const float*)d_in[9];
  const float* n2b = (const float*)d_in[10];
  float* out = (float*)d_out;

  char* ws = (char*)d_ws;
  size_t off = 0;
  auto alloc = [&](size_t bytes) {
    char* p = ws + off;
    off = (off + bytes + 255) & ~(size_t)255;
    return p;
  };
  unsigned short* base_bf = (unsigned short*)alloc((size_t)ROWS * DM_ * 2);
  unsigned short* Wqkvt = (unsigned short*)alloc((size_t)QKVN * DM_ * 2);
  unsigned short* W1t = (unsigned short*)alloc((size_t)DM_ * DM_ * 2);
  unsigned short* W2t = (unsigned short*)alloc((size_t)DM_ * DM_ * 2);
  unsigned short* qkvb = (unsigned short*)alloc((size_t)ROWS * QKVN * 2);
  unsigned short* Vtb = (unsigned short*)alloc((size_t)B_ * H_ * HD_ * S_ * 2);
  unsigned short* avb = (unsigned short*)alloc((size_t)ROWS * DM_ * 2);
  unsigned short* t1b = (unsigned short*)alloc((size_t)ROWS * DM_ * 2);   // reused for t2
  unsigned short* hbf = (unsigned short*)alloc((size_t)ROWS * DM_ * 2);

  prep<<<CVT_B + WQ_B + 2 * W1_B, 256, 0, stream>>>(
      base, base_bf, Wqkv, Wqkvt, W1, W1t, W2, W2t);
  gemm_qkv<<<dim3(QKVN / 128, ROWS / 128), 256, 0, stream>>>(
      base_bf, Wqkvt, bqkv, qkvb, ROWS, QKVN, DM_);
  vtrans<<<dim3(S_ / 64, B_ * H_), 256, 0, stream>>>(qkvb, Vtb);
  attn<<<dim3(S_ / 128, B_ * H_), 256, 0, stream>>>(qkvb, Vtb, avb);
  gemm64<1><<<dim3(DM_ / 128, ROWS / 64), 256, 0, stream>>>(
      avb, W1t, b1, base_bf, t1b, ROWS, DM_, DM_);
  normk<1><<<ROWS, 256, 0, stream>>>(t1b, n1s, n1b, nullptr, hbf);
  gemm64<2><<<dim3(DM_ / 128, ROWS / 64), 256, 0, stream>>>(
      hbf, W2t, b2, hbf, t1b, ROWS, DM_, DM_);
  normk<0><<<ROWS, 256, 0, stream>>>(t1b, n2s, n2b, out, nullptr);
}

// Round 9
// 254.683 us; speedup vs baseline: 1.1055x; 1.0136x over previous
//
#include <hip/hip_runtime.h>
#include <hip/hip_bf16.h>
#include <stdint.h>

#define B_ 4
#define S_ 2048
#define DM_ 768
#define H_ 12
#define HD_ 64
#define ROWS (B_*S_)      // 8192
#define QKVN (3*DM_)      // 2304

typedef __attribute__((ext_vector_type(8))) short short8;
typedef __attribute__((ext_vector_type(4))) float floatx4;
typedef __attribute__((ext_vector_type(8))) unsigned short ushort8;
typedef __attribute__((ext_vector_type(4))) unsigned short ushort4v;
typedef __attribute__((ext_vector_type(4))) float float4_t;

__device__ __forceinline__ unsigned short f2b(float f) {
  union { float f; uint32_t u; } x; x.f = f;
  uint32_t r = x.u + 0x7FFFu + ((x.u >> 16) & 1u);
  return (unsigned short)(r >> 16);
}
__device__ __forceinline__ float b2f(unsigned short u) {
  union { uint32_t u; float f; } x; x.u = ((uint32_t)u) << 16; return x.f;
}
__device__ __forceinline__ uint32_t fbits(float f) {
  union { float f; uint32_t u; } x; x.f = f; return x.u;
}

// async global->LDS, 16B per lane. LDS dest is wave-uniform base + lane*16.
__device__ __forceinline__ void load_lds16(const void* g, void* l) {
  __builtin_amdgcn_global_load_lds(
      (const __attribute__((address_space(1))) uint32_t*)g,
      (__attribute__((address_space(3))) uint32_t*)l, 16, 0, 0);
}

// ---------------- fused prep: base cast + 3 weight transposes ----------------
// block ranges: [0,6144) cvt | [6144,7872) Wqkv | [7872,8448) W1 | [8448,9024) W2
#define CVT_B 6144
#define WQ_B 1728
#define W1_B 576
__global__ __launch_bounds__(256) void prep(
    const float* __restrict__ base, unsigned short* __restrict__ base_bf,
    const float* __restrict__ Wqkv, unsigned short* __restrict__ Wqkvt,
    const float* __restrict__ W1, unsigned short* __restrict__ W1t,
    const float* __restrict__ W2, unsigned short* __restrict__ W2t) {
  __shared__ float t[32][33];
  int bid = blockIdx.x;
  int tid = threadIdx.x;
  if (bid < CVT_B) {
    int i = bid * 256 + tid;
    float4_t v = ((const float4_t*)base)[i];
    ushort4v o;
    o[0] = f2b(v[0]); o[1] = f2b(v[1]); o[2] = f2b(v[2]); o[3] = f2b(v[3]);
    ((ushort4v*)base_bf)[i] = o;
    return;
  }
  const float* W; unsigned short* Wt; int N, rel;
  if (bid < CVT_B + WQ_B)      { W = Wqkv; Wt = Wqkvt; N = QKVN; rel = bid - CVT_B; }
  else if (bid < CVT_B + WQ_B + W1_B) { W = W1; Wt = W1t; N = DM_; rel = bid - CVT_B - WQ_B; }
  else                          { W = W2; Wt = W2t; N = DM_; rel = bid - CVT_B - WQ_B - W1_B; }
  int K = DM_;
  int n0 = (rel % (N / 32)) * 32, k0 = (rel / (N / 32)) * 32;
  int tx = tid & 31, ty = tid >> 5;  // ty 0..7
#pragma unroll
  for (int i = 0; i < 4; i++)
    t[ty + i * 8][tx] = W[(size_t)(k0 + ty + i * 8) * N + n0 + tx];
  __syncthreads();
#pragma unroll
  for (int i = 0; i < 4; i++)
    Wt[(size_t)(n0 + ty + i * 8) * K + k0 + tx] = f2b(t[tx][ty + i * 8]);
}

// ---------------- bf16 MFMA GEMM (128x128 tile, BK=128): QKV + fused V-transpose ----------
// XOR-swizzled LDS (16 chunks/row): chunk c of row r stored at position c^(r&15).
// Epilogue: Q cols pre-scaled by 0.125*log2(e); V-blocks (n0>=2*DM) write transposed
// permuted Vt directly (via per-wave LDS scratch) and skip the qkv store.
__global__ __launch_bounds__(256, 2) void gemm_qkv(
    const unsigned short* __restrict__ A,
    const unsigned short* __restrict__ Bt,
    const float* __restrict__ bias,
    unsigned short* __restrict__ Cout,
    unsigned short* __restrict__ Vt,
    int M, int N, int K) {
  __shared__ __align__(16) unsigned short LDSbuf[2 * 128 * 128];  // As | Bs (64 KB)
  unsigned short* As = LDSbuf;
  unsigned short* Bs = LDSbuf + 128 * 128;
  int tid = threadIdx.x;
  int wave = tid >> 6, lane = tid & 63;
  int quad = lane >> 4, l16 = lane & 15;
  int sr4 = lane >> 4;                // staging row within 4-row op
  int c16 = lane & 15;                // staging chunk position
  int m0 = blockIdx.y * 128, n0 = blockIdx.x * 128;
  int wm = (wave >> 1) * 64, wn = (wave & 1) * 64;
  floatx4 acc[4][4] = {};

  for (int kb = 0; kb < K; kb += 128) {
#pragma unroll
    for (int i = 0; i < 8; i++) {
      int op = wave * 8 + i;
      int srow = op * 4 + sr4;
      int sc = c16 ^ (srow & 15);
      load_lds16(A + (size_t)(m0 + srow) * K + kb + sc * 8, (char*)As + op * 1024);
    }
#pragma unroll
    for (int i = 0; i < 8; i++) {
      int op = wave * 8 + i;
      int srow = op * 4 + sr4;
      int sc = c16 ^ (srow & 15);
      load_lds16(Bt + (size_t)(n0 + srow) * K + kb + sc * 8, (char*)Bs + op * 1024);
    }
    __syncthreads();  // drains vmcnt + barrier
#pragma unroll
    for (int ks = 0; ks < 4; ks++) {
      short8 af[4], bfr[4];
#pragma unroll
      for (int mt = 0; mt < 4; mt++)
        af[mt] = *(const short8*)(As + (wm + mt * 16 + l16) * 128 + ((ks * 4 + quad) ^ l16) * 8);
#pragma unroll
      for (int nt = 0; nt < 4; nt++)
        bfr[nt] = *(const short8*)(Bs + (wn + nt * 16 + l16) * 128 + ((ks * 4 + quad) ^ l16) * 8);
#pragma unroll
      for (int mt = 0; mt < 4; mt++)
#pragma unroll
        for (int nt = 0; nt < 4; nt++)
          acc[mt][nt] = __builtin_amdgcn_mfma_f32_16x16x32_bf16(af[mt], bfr[nt], acc[mt][nt], 0, 0, 0);
    }
    __syncthreads();  // also guarantees all ds_reads done before epilogue LDS reuse
  }

  if (n0 < 2 * DM_) {
    // Q/K epilogue: scalar bf16 stores to qkv
#pragma unroll
    for (int mt = 0; mt < 4; mt++) {
#pragma unroll
      for (int nt = 0; nt < 4; nt++) {
#pragma unroll
        for (int r = 0; r < 4; r++) {
          int row = m0 + wm + mt * 16 + quad * 4 + r;
          int col = n0 + wn + nt * 16 + l16;
          float v = acc[mt][nt][r] + bias[col];
          if (col < DM_) v *= 0.18033688011112042f;  // 0.125*log2(e): pre-scale Q
          Cout[(size_t)row * N + col] = f2b(v);
        }
      }
    }
  } else {
    // V epilogue: transpose + key-permute into Vt[(b*H+h)*64 + d][s]
    // wave tile = 64 s-rows (wm) x 64 d-cols (one head, wn).
    // scratch row stride 72 ushorts (conflict-free in 8-lane groups).
    unsigned short* scr = LDSbuf + wave * 4608;
    int h = (n0 + wn - 2 * DM_) >> 6;
    int b = m0 >> 11;
    int s_base = (m0 & (S_ - 1)) + wm;
#pragma unroll
    for (int nt = 0; nt < 4; nt++) {
      float bv = bias[n0 + wn + nt * 16 + l16];
      ushort8 v0, v1;
#pragma unroll
      for (int j = 0; j < 8; j++) {
        v0[j] = f2b(acc[j & 3][nt][j >> 2] + bv);
        v1[j] = f2b(acc[j & 3][nt][2 + (j >> 2)] + bv);
      }
      // pos = 16*quad + 4r + mt holds acc[mt][nt][r]  (perm(s)= (s&15)*4+(s>>4))
      *(ushort8*)(scr + (nt * 16 + l16) * 72 + quad * 16) = v0;
      *(ushort8*)(scr + (nt * 16 + l16) * 72 + quad * 16 + 8) = v1;
    }
    // read back rows of d, write coalesced to Vt (same-wave: compiler inserts lgkmcnt)
#pragma unroll
    for (int it = 0; it < 8; it++) {
      int d = it * 8 + (lane >> 3);
      int ch = lane & 7;
      ushort8 w = *(const ushort8*)(scr + d * 72 + ch * 8);
      *(ushort8*)(Vt + ((size_t)(b * H_ + h) * 64 + d) * S_ + s_base + ch * 8) = w;
    }
  }
}

// ---------------- bf16 MFMA GEMM (64x128 tile, 4 blocks/CU): MLP GEMMs ----------------
// EPI=1: bias + res(bf16) -> bf16 out. EPI=2: relu(bias) + res(bf16) -> bf16 out.
template <int EPI>
__global__ __launch_bounds__(256, 4) void gemm64(
    const unsigned short* __restrict__ A,
    const unsigned short* __restrict__ Bt,
    const float* __restrict__ bias,
    const unsigned short* __restrict__ res,
    unsigned short* __restrict__ Cout,
    int M, int N, int K) {
  __shared__ __align__(16) unsigned short As[64 * 64];
  __shared__ __align__(16) unsigned short Bs[128 * 64];
  int tid = threadIdx.x;
  int wave = tid >> 6, lane = tid & 63;
  int quad = lane >> 4, l16 = lane & 15;
  int e = l16 & 7;
  int sr = lane >> 3;
  int sc = (lane & 7) ^ (sr & 7);
  int m0 = blockIdx.y * 64, n0 = blockIdx.x * 128;
  int wm = (wave >> 1) * 32, wn = (wave & 1) * 64;
  floatx4 acc[2][4] = {};

  for (int kb = 0; kb < K; kb += 64) {
#pragma unroll
    for (int i = 0; i < 2; i++) {
      int op = wave * 2 + i;  // 8 A ops
      load_lds16(A + (size_t)(m0 + op * 8 + sr) * K + kb + sc * 8, (char*)As + op * 1024);
    }
#pragma unroll
    for (int i = 0; i < 4; i++) {
      int op = wave * 4 + i;  // 16 B ops
      load_lds16(Bt + (size_t)(n0 + op * 8 + sr) * K + kb + sc * 8, (char*)Bs + op * 1024);
    }
    __syncthreads();
#pragma unroll
    for (int ks = 0; ks < 2; ks++) {
      short8 af[2], bfr[4];
#pragma unroll
      for (int mt = 0; mt < 2; mt++)
        af[mt] = *(const short8*)(As + (wm + mt * 16 + l16) * 64 + ((ks * 4 + quad) ^ e) * 8);
#pragma unroll
      for (int nt = 0; nt < 4; nt++)
        bfr[nt] = *(const short8*)(Bs + (wn + nt * 16 + l16) * 64 + ((ks * 4 + quad) ^ e) * 8);
#pragma unroll
      for (int mt = 0; mt < 2; mt++)
#pragma unroll
        for (int nt = 0; nt < 4; nt++)
          acc[mt][nt] = __builtin_amdgcn_mfma_f32_16x16x32_bf16(af[mt], bfr[nt], acc[mt][nt], 0, 0, 0);
    }
    __syncthreads();
  }
#pragma unroll
  for (int mt = 0; mt < 2; mt++) {
#pragma unroll
    for (int nt = 0; nt < 4; nt++) {
#pragma unroll
      for (int r = 0; r < 4; r++) {
        int row = m0 + wm + mt * 16 + quad * 4 + r;
        int col = n0 + wn + nt * 16 + l16;
        size_t idx = (size_t)row * N + col;
        float v = acc[mt][nt][r] + bias[col];
        if (EPI == 2) v = fmaxf(v, 0.0f);
        v += b2f(res[idx]);
        Cout[idx] = f2b(v);
      }
    }
  }
}

// ---------------- flash attention: av = softmax(Q K^T / 8) V ----------------
// 4 waves x 32 q-rows (12 waves/CU). Q pre-scaled by 0.125*log2(e) in the QKV GEMM,
// so p = exp2(sv) directly. Staging addresses strength-reduced to pointer increments.
// Q staged into each wave's private Ps slab (read once into regs, space reused for P).
// XOR-swizzled Ks/Vs; P packed 4-wide (permuted key order matching Vt) via v_perm ->
// ds_write_b64; no running max; denominator via MFMA with ones.
__global__ __launch_bounds__(256, 2) void attn(
    const unsigned short* __restrict__ qkv,
    const unsigned short* __restrict__ Vt,
    unsigned short* __restrict__ av) {
  int qt = blockIdx.x;   // q-tile 0..15 (128 rows)
  int bh = blockIdx.y;   // 0..47
  int b = bh / H_, h = bh % H_;
  int row0 = b * S_ + qt * 128;
  __shared__ __align__(16) unsigned short Ks[2][64 * 64];
  __shared__ __align__(16) unsigned short Vs[2][64 * 64];
  __shared__ __align__(16) unsigned short Ps[4][32 * 72];  // row stride 144B; doubles as Q staging
  int tid = threadIdx.x;
  int wave = tid >> 6, lane = tid & 63;
  int quad = lane >> 4, l16 = lane & 15;
  int e = l16 & 7;
  int sr = lane >> 3;
  int sc = (lane & 7) ^ (sr & 7);

  // stage this wave's 32 Q rows into its own Ps slab (row stride 128B, swizzled chunks)
#pragma unroll
  for (int i = 0; i < 4; i++) {
    load_lds16(qkv + (size_t)(row0 + wave * 32 + i * 8 + sr) * QKVN + h * HD_ + sc * 8,
               (char*)Ps[wave] + i * 1024);
  }
  // lane-constant staging pointers; advanced by fixed strides per K-tile
  const unsigned short* kp = qkv + (size_t)(b * S_ + wave * 16 + sr) * QKVN + DM_ + h * HD_ + sc * 8;
  const unsigned short* vp = Vt + ((size_t)bh * 64 + wave * 16 + sr) * S_ + sc * 8;
  auto stageKV = [&](const unsigned short* kq, const unsigned short* vq, int buf) {
#pragma unroll
    for (int i = 0; i < 2; i++) {
      load_lds16(kq + (size_t)i * 8 * QKVN, (char*)Ks[buf] + wave * 2048 + i * 1024);
      load_lds16(vq + (size_t)i * 8 * S_, (char*)Vs[buf] + wave * 2048 + i * 1024);
    }
  };
  stageKV(kp, vp, 0);

  floatx4 accO[2][4] = {};
  floatx4 accL[2] = {};
  short8 ones;
#pragma unroll
  for (int j = 0; j < 8; j++) ones[j] = (short)0x3F80;  // bf16 1.0
  __syncthreads();  // Q + KV(0) staged (drains vmcnt)

  // hoist Q fragments from this wave's Ps slab (before any P write; same-wave ordering)
  short8 qf[2][2];
#pragma unroll
  for (int mf = 0; mf < 2; mf++)
#pragma unroll
    for (int ks = 0; ks < 2; ks++)
      qf[mf][ks] = *(const short8*)(Ps[wave] + (mf * 16 + l16) * 64 + ((ks * 4 + quad) ^ e) * 8);

  int cur = 0;
  for (int kt = 0; kt < 32; kt++) {
    floatx4 sv[2][4] = {};
#pragma unroll
    for (int ks = 0; ks < 2; ks++)
#pragma unroll
      for (int nt = 0; nt < 4; nt++) {
        short8 kf = *(const short8*)(Ks[cur] + (nt * 16 + l16) * 64 + ((ks * 4 + quad) ^ e) * 8);
#pragma unroll
        for (int mf = 0; mf < 2; mf++)
          sv[mf][nt] = __builtin_amdgcn_mfma_f32_16x16x32_bf16(qf[mf][ks], kf, sv[mf][nt], 0, 0, 0);
      }
    // prefetch next K/V now: overlaps softmax + PV below
    if (kt + 1 < 32) {
      kp += 64 * QKVN;
      vp += 64;
      stageKV(kp, vp, cur ^ 1);
    }
    // p = exp2(sv) (scale folded into Q); pack 4 bf16 -> b64 write
#pragma unroll
    for (int mf = 0; mf < 2; mf++)
#pragma unroll
      for (int r = 0; r < 4; r++) {
        uint32_t u0 = fbits(__builtin_amdgcn_exp2f(sv[mf][0][r]));
        uint32_t u1 = fbits(__builtin_amdgcn_exp2f(sv[mf][1][r]));
        uint32_t u2 = fbits(__builtin_amdgcn_exp2f(sv[mf][2][r]));
        uint32_t u3 = fbits(__builtin_amdgcn_exp2f(sv[mf][3][r]));
        uint2 val;
        val.x = __builtin_amdgcn_perm(u1, u0, 0x07060302u);  // [u0.hi16, u1.hi16]
        val.y = __builtin_amdgcn_perm(u3, u2, 0x07060302u);  // [u2.hi16, u3.hi16]
        *(uint2*)(&Ps[wave][(mf * 16 + quad * 4 + r) * 72 + l16 * 4]) = val;
      }
#pragma unroll
    for (int ks = 0; ks < 2; ks++) {
      short8 pf[2];
#pragma unroll
      for (int mf = 0; mf < 2; mf++) {
        pf[mf] = *(const short8*)(Ps[wave] + (mf * 16 + l16) * 72 + ks * 32 + quad * 8);
        accL[mf] = __builtin_amdgcn_mfma_f32_16x16x32_bf16(pf[mf], ones, accL[mf], 0, 0, 0);
      }
#pragma unroll
      for (int nt = 0; nt < 4; nt++) {
        short8 vf = *(const short8*)(Vs[cur] + (nt * 16 + l16) * 64 + ((ks * 4 + quad) ^ e) * 8);
#pragma unroll
        for (int mf = 0; mf < 2; mf++)
          accO[mf][nt] = __builtin_amdgcn_mfma_f32_16x16x32_bf16(pf[mf], vf, accO[mf][nt], 0, 0, 0);
      }
    }
    __syncthreads();  // drains prefetch vmcnt; all waves done with cur
    cur ^= 1;
  }
#pragma unroll
  for (int mf = 0; mf < 2; mf++)
#pragma unroll
    for (int r = 0; r < 4; r++) {
      float inv = 1.0f / accL[mf][r];
      int row = row0 + wave * 32 + mf * 16 + quad * 4 + r;
#pragma unroll
      for (int nt = 0; nt < 4; nt++)
        av[(size_t)row * DM_ + h * HD_ + nt * 16 + l16] = f2b(accO[mf][nt][r] * inv);
    }
}

// ---------------- row norm: (x-mean)/std * scale + bias (bf16 input) ----------------
// WB=1: write bf16 only. WB=0: write f32 only (final output).
template <int WB>
__global__ __launch_bounds__(256) void normk(
    const unsigned short* __restrict__ X, const float* __restrict__ scale,
    const float* __restrict__ bias, float* __restrict__ Y,
    unsigned short* __restrict__ Ybf) {
  int row = blockIdx.x;
  const unsigned short* x = X + (size_t)row * DM_;
  int tid = threadIdx.x;
  int wave = tid >> 6, lane = tid & 63;
  float v[3];
#pragma unroll
  for (int i = 0; i < 3; i++) v[i] = b2f(x[tid + i * 256]);
  float s = v[0] + v[1] + v[2];
#pragma unroll
  for (int o = 32; o > 0; o >>= 1) s += __shfl_xor(s, o);
  __shared__ float red[4];
  if (lane == 0) red[wave] = s;
  __syncthreads();
  float mean = (red[0] + red[1] + red[2] + red[3]) * (1.0f / DM_);
  float ss = 0.0f;
#pragma unroll
  for (int i = 0; i < 3; i++) { v[i] -= mean; ss += v[i] * v[i]; }
#pragma unroll
  for (int o = 32; o > 0; o >>= 1) ss += __shfl_xor(ss, o);
  __syncthreads();
  if (lane == 0) red[wave] = ss;
  __syncthreads();
  float var = (red[0] + red[1] + red[2] + red[3]) * (1.0f / DM_);
  float rstd = rsqrtf(var);
  float sg = scale[0], bg = bias[0];
#pragma unroll
  for (int i = 0; i < 3; i++) {
    float y = v[i] * rstd * sg + bg;
    if (WB) Ybf[(size_t)row * DM_ + tid + i * 256] = f2b(y);
    else    Y[(size_t)row * DM_ + tid + i * 256] = y;
  }
}

extern "C" void kernel_launch(void* const* d_in, const int* in_sizes, int n_in,
                              void* d_out, int out_size, void* d_ws, size_t ws_size,
                              hipStream_t stream) {
  const float* base = (const float*)d_in[0];
  const float* Wqkv = (const float*)d_in[1];
  const float* bqkv = (const float*)d_in[2];
  const float* W1 = (const float*)d_in[3];
  const float* b1 = (const float*)d_in[4];
  const float* W2 = (const float*)d_in[5];
  const float* b2 = (const float*)d_in[6];
  const float* n1s = (const float*)d_in[7];
  const float* n1b = (const float*)d_in[8];
  const float* n2s = (const float*)d_in[9];
  const float* n2b = (const float*)d_in[10];
  float* out = (float*)d_out;

  char* ws = (char*)d_ws;
  size_t off = 0;
  auto alloc = [&](size_t bytes) {
    char* p = ws + off;
    off = (off + bytes + 255) & ~(size_t)255;
    return p;
  };
  unsigned short* base_bf = (unsigned short*)alloc((size_t)ROWS * DM_ * 2);
  unsigned short* Wqkvt = (unsigned short*)alloc((size_t)QKVN * DM_ * 2);
  unsigned short* W1t = (unsigned short*)alloc((size_t)DM_ * DM_ * 2);
  unsigned short* W2t = (unsigned short*)alloc((size_t)DM_ * DM_ * 2);
  unsigned short* qkvb = (unsigned short*)alloc((size_t)ROWS * QKVN * 2);
  unsigned short* Vtb = (unsigned short*)alloc((size_t)B_ * H_ * HD_ * S_ * 2);
  unsigned short* avb = (unsigned short*)alloc((size_t)ROWS * DM_ * 2);
  unsigned short* t1b = (unsigned short*)alloc((size_t)ROWS * DM_ * 2);   // reused for t2
  unsigned short* hbf = (unsigned short*)alloc((size_t)ROWS * DM_ * 2);

  prep<<<CVT_B + WQ_B + 2 * W1_B, 256, 0, stream>>>(
      base, base_bf, Wqkv, Wqkvt, W1, W1t, W2, W2t);
  gemm_qkv<<<dim3(QKVN / 128, ROWS / 128), 256, 0, stream>>>(
      base_bf, Wqkvt, bqkv, qkvb, Vtb, ROWS, QKVN, DM_);
  attn<<<dim3(S_ / 128, B_ * H_), 256, 0, stream>>>(qkvb, Vtb, avb);
  gemm64<1><<<dim3(DM_ / 128, ROWS / 64), 256, 0, stream>>>(
      avb, W1t, b1, base_bf, t1b, ROWS, DM_, DM_);
  normk<1><<<ROWS, 256, 0, stream>>>(t1b, n1s, n1b, nullptr, hbf);
  gemm64<2><<<dim3(DM_ / 128, ROWS / 64), 256, 0, stream>>>(
      hbf, W2t, b2, hbf, t1b, ROWS, DM_, DM_);
  normk<0><<<ROWS, 256, 0, stream>>>(t1b, n2s, n2b, out, nullptr);
}